// Round 7
// baseline (489.092 us; speedup 1.0000x reference)
//
#include <hip/hip_runtime.h>
#include <math.h>

#define NTOK 4096

typedef __attribute__((ext_vector_type(8))) short short8;
typedef __attribute__((ext_vector_type(4))) float floatx4;

static __device__ __forceinline__ unsigned short f2bf(float f) {
    unsigned int u = __float_as_uint(f);
    unsigned int r = (u + 0x7fffu + ((u >> 16) & 1u)) >> 16;
    return (unsigned short)r;
}

// async global->LDS, 16B per lane. LDS dest = wave-uniform base + lane*16.
static __device__ __forceinline__ void gload16(const void* g, void* l) {
    __builtin_amdgcn_global_load_lds(
        (const __attribute__((address_space(1))) void*)g,
        (__attribute__((address_space(3))) void*)(unsigned int)(unsigned long long)l,
        16, 0, 0);
}

#define WAIT_VM4()  asm volatile("s_waitcnt vmcnt(4)" ::: "memory")
#define WAIT_VM0()  asm volatile("s_waitcnt vmcnt(0)" ::: "memory")
#define WAIT_LGKM() asm volatile("s_waitcnt lgkmcnt(0)" ::: "memory")

// stage: 128 rows x 32 bf16 = 4096 shorts = 8 KB (A and B each)
#define STG 4096

// ---------------- merged cvt (6 arrays) + compact (y==6) ----------------
// counters/loss zeroed by hipMemsetAsync before this launch.
__global__ void cvt_all_k(const float* __restrict__ s0, unsigned short* __restrict__ d0, int e0,
                          const float* __restrict__ s1, unsigned short* __restrict__ d1, int e1,
                          const float* __restrict__ s2, unsigned short* __restrict__ d2, int e2,
                          const float* __restrict__ s3, unsigned short* __restrict__ d3, int e3,
                          const float* __restrict__ s4, unsigned short* __restrict__ d4, int e4,
                          const float* __restrict__ s5, unsigned short* __restrict__ d5, int e5,
                          const int* __restrict__ target,
                          int* __restrict__ idx0, int* __restrict__ lab0, int* __restrict__ n0,
                          int* __restrict__ idx1, int* __restrict__ lab1, int* __restrict__ n1,
                          int* __restrict__ labh) {
    int y = blockIdx.y;
    if (y == 6) {
        int i = blockIdx.x * blockDim.x + threadIdx.x;
        if (i >= NTOK) return;
        int t = target[i];
        int ft = t;
        if (t >= 2000 && t < 10000) {
            int p = atomicAdd(n0, 1);
            idx0[p] = i; lab0[p] = t - 2000; ft = 2000;
        } else if (t >= 10000) {
            int p = atomicAdd(n1, 1);
            idx1[p] = i; lab1[p] = t - 10000; ft = 2001;
        }
        labh[i] = ft;
        return;
    }
    const float* s; unsigned short* d; int n;
    switch (y) {
        case 0: s = s0; d = d0; n = e0; break;
        case 1: s = s1; d = d1; n = e1; break;
        case 2: s = s2; d = d2; n = e2; break;
        case 3: s = s3; d = d3; n = e3; break;
        case 4: s = s4; d = d4; n = e4; break;
        default: s = s5; d = d5; n = e5; break;
    }
    int stride = gridDim.x * blockDim.x * 4;
    for (int i = (blockIdx.x * blockDim.x + threadIdx.x) * 4; i < n; i += stride) {
        float4 v = *(const float4*)(s + i);
        ushort4 o;
        o.x = f2bf(v.x); o.y = f2bf(v.y); o.z = f2bf(v.z); o.w = f2bf(v.w);
        *(ushort4*)(d + i) = o;
    }
}

// ---------------- merged gathered h-GEMM, 3-stage issue-after-barrier ----------------
__global__ __launch_bounds__(256)
void hgemm_all_k(const unsigned short* __restrict__ win,
                 const unsigned short* __restrict__ t0w1, unsigned short* __restrict__ h0o,
                 const int* __restrict__ idx0, const int* __restrict__ n0p,
                 const unsigned short* __restrict__ t1w1, unsigned short* __restrict__ h1o,
                 const int* __restrict__ idx1, const int* __restrict__ n1p) {
    __shared__ unsigned short Asm[3 * STG];
    __shared__ unsigned short Bsm[3 * STG];
    __shared__ int sidx[128];
    int bid = blockIdx.x;
    const unsigned short* B; unsigned short* H; const int* idx; int n, P, rb, cb;
    if (bid < 256) { rb = bid >> 3; cb = bid & 7; B = t0w1; H = h0o; idx = idx0; n = *n0p; P = 1024; }
    else { int b = bid - 256; rb = b >> 1; cb = b & 1; B = t1w1; H = h1o; idx = idx1; n = *n1p; P = 256; }
    const int K = 1024, T = 32;
    int row_base = rb * 128;
    if (row_base >= n) return;
    int col_base = cb * 128;
    int t = threadIdx.x;
    int wave = t >> 6, lane = t & 63;
    int wrow = (wave >> 1) * 64, wcol = (wave & 1) * 64;
    int fr = lane & 15, fk = lane >> 4;

    if (t < 128) { int r = row_base + t; sidx[t] = idx[r < n ? r : n - 1]; }
    __syncthreads();   // drains vmcnt: clean slate before manual pipeline

    int sr0 = wave * 32 + (lane >> 2);
    int sr1 = sr0 + 16;
    int c0l = lane & 3;
    int gc0 = c0l ^ ((sr0 >> 1) & 3);
    int gc1 = c0l ^ ((sr1 >> 1) & 3);
    const unsigned short* Ab0 = win + (size_t)sidx[sr0] * K + gc0 * 8;
    const unsigned short* Ab1 = win + (size_t)sidx[sr1] * K + gc1 * 8;
    const unsigned short* Bb0 = B + (size_t)(col_base + sr0) * K + gc0 * 8;
    const unsigned short* Bb1 = B + (size_t)(col_base + sr1) * K + gc1 * 8;

    auto issue = [&](int s, int slot) {
        int koff = s << 5;
        unsigned short* as = Asm + slot * STG + wave * 1024;
        unsigned short* bs = Bsm + slot * STG + wave * 1024;
        gload16(Ab0 + koff, as); gload16(Ab1 + koff, as + 512);
        gload16(Bb0 + koff, bs); gload16(Bb1 + koff, bs + 512);
    };

    int sw = (fk ^ ((fr >> 1) & 3)) * 8;
    int ra[4], rc[4];
#pragma unroll
    for (int i = 0; i < 4; ++i) {
        ra[i] = (wrow + i * 16 + fr) * 32 + sw;
        rc[i] = (wcol + i * 16 + fr) * 32 + sw;
    }

    issue(0, 0); issue(1, 1);
    floatx4 acc[4][4] = {};
    int sc = 0, si = 2;
    for (int j = 0; j < T; ++j) {
        if (j < T - 1) { WAIT_VM4(); } else { WAIT_VM0(); }
        WAIT_LGKM();
        __builtin_amdgcn_s_barrier();
        if (j + 2 < T) { issue(j + 2, si); si = (si == 2) ? 0 : si + 1; }
        const unsigned short* As = Asm + sc * STG;
        const unsigned short* Bs = Bsm + sc * STG;
        sc = (sc == 2) ? 0 : sc + 1;
        short8 af[4], bf[4];
#pragma unroll
        for (int i = 0; i < 4; ++i) af[i] = *(const short8*)&As[ra[i]];
#pragma unroll
        for (int i = 0; i < 4; ++i) bf[i] = *(const short8*)&Bs[rc[i]];
#pragma unroll
        for (int rt = 0; rt < 4; ++rt)
#pragma unroll
            for (int ct = 0; ct < 4; ++ct)
                acc[rt][ct] = __builtin_amdgcn_mfma_f32_16x16x32_bf16(af[rt], bf[ct], acc[rt][ct], 0, 0, 0);
    }
#pragma unroll
    for (int rt = 0; rt < 4; ++rt)
#pragma unroll
        for (int r = 0; r < 4; ++r) {
            int row = row_base + wrow + rt * 16 + fk * 4 + r;
#pragma unroll
            for (int ct = 0; ct < 4; ++ct) {
                int col = col_base + wcol + ct * 16 + fr;
                H[(size_t)row * P + col] = f2bf(acc[rt][ct][r]);
            }
        }
}

// ---------------- CE: uniform-duration blocks (T=32), vmem-FREE in-loop epilogue ----------------
// The mid-loop epilogue (tail1 chunk groups) must not issue ANY vmem op: a global
// store/load there increments vmcnt and corrupts the manual s_waitcnt vmcnt(4)
// pipeline accounting (round-5/6 regression). Label logits therefore accumulate in
// registers and are written once per block, after the final vmcnt(0).
// seg1 (bid<2528):    tail1 V=40000 K=256,  4 chunks/block (79 groups x 32 rb)
// seg0 (2528..4543):  tail0 V=8000  K=1024, 1 chunk/block  (63 groups x 32 rb)
// segh (4544..5055):  head  V=2002  K=1024, 1 chunk/block  (16 groups x 32 rb, +bias;
//                     cpg=1 -> its epilogue runs only on the last iter, after VM0)
__global__ __launch_bounds__(256)
void ce_all_k(const unsigned short* __restrict__ h1, const unsigned short* __restrict__ t1w2,
              const int* __restrict__ lab1, const int* __restrict__ n1p,
              float* __restrict__ ps1, float* __restrict__ ll1,
              const unsigned short* __restrict__ h0, const unsigned short* __restrict__ t0w2,
              const int* __restrict__ lab0, const int* __restrict__ n0p,
              float* __restrict__ ps0, float* __restrict__ ll0,
              const unsigned short* __restrict__ win, const unsigned short* __restrict__ hw,
              const float* __restrict__ head_b, const int* __restrict__ labh,
              float* __restrict__ psh, float* __restrict__ llh) {
    __shared__ unsigned short Asm[3 * STG];
    __shared__ unsigned short Bsm[3 * STG];
    __shared__ int slab[128];
    __shared__ float cs[128][2];
    __shared__ float cl[128][2];
    int bid = blockIdx.x;
    const unsigned short* A; const unsigned short* B; const float* bias = nullptr;
    const int* labels; int n, V, kbits, nkb, cpg, nch, g, rb;
    float* ps; float* ll;
    if (bid < 2528) {
        g = bid >> 5; rb = bid & 31;
        A = h1; B = t1w2; labels = lab1; n = *n1p; V = 40000; kbits = 8; nkb = 3;
        nch = 313; cpg = 4; ps = ps1; ll = ll1;
    } else if (bid < 4544) {
        int b = bid - 2528; g = b >> 5; rb = b & 31;
        A = h0; B = t0w2; labels = lab0; n = *n0p; V = 8000; kbits = 10; nkb = 5;
        nch = 63; cpg = 1; ps = ps0; ll = ll0;
    } else {
        int b = bid - 4544; g = b >> 5; rb = b & 31;
        A = win; B = hw; labels = labh; n = NTOK; V = 2002; kbits = 10; nkb = 5;
        nch = 16; cpg = 1; ps = psh; ll = llh; bias = head_b;
    }
    int row_base = rb * 128;
    if (row_base >= n) return;
    int chunk0 = g * cpg;
    int cpga = nch - chunk0; if (cpga > cpg) cpga = cpg;
    int NKm = (1 << nkb) - 1;
    int T = cpga << nkb;
    int t = threadIdx.x;
    int wave = t >> 6, lane = t & 63;
    int wrow = (wave >> 1) * 64, wcol = (wave & 1) * 64;
    int fr = lane & 15, fk = lane >> 4;

    if (t < 128) slab[t] = labels[row_base + t];
    __syncthreads();   // drains vmcnt: clean slate before manual pipeline

    int sr0 = wave * 32 + (lane >> 2);
    int sr1 = sr0 + 16;
    int c0l = lane & 3;
    int gc0 = c0l ^ ((sr0 >> 1) & 3);
    int gc1 = c0l ^ ((sr1 >> 1) & 3);
    const unsigned short* Ab0 = A + (((size_t)(row_base + sr0)) << kbits) + gc0 * 8;
    const unsigned short* Ab1 = A + (((size_t)(row_base + sr1)) << kbits) + gc1 * 8;
    int colb0 = chunk0 << 7;
    int Vm1 = V - 1;

    auto issue = [&](int s, int slot) {
        int ck = s >> nkb, kk = s & NKm;
        int koff = kk << 5;
        int colb = colb0 + (ck << 7);
        int br0 = colb + sr0; if (br0 > Vm1) br0 = Vm1;
        int br1 = colb + sr1; if (br1 > Vm1) br1 = Vm1;
        const unsigned short* b0 = B + (((size_t)br0) << kbits) + gc0 * 8 + koff;
        const unsigned short* b1 = B + (((size_t)br1) << kbits) + gc1 * 8 + koff;
        unsigned short* as = Asm + slot * STG + wave * 1024;
        unsigned short* bs = Bsm + slot * STG + wave * 1024;
        gload16(Ab0 + koff, as); gload16(Ab1 + koff, as + 512);
        gload16(b0, bs); gload16(b1, bs + 512);
    };

    int sw = (fk ^ ((fr >> 1) & 3)) * 8;
    int ra[4], rc[4];
#pragma unroll
    for (int i = 0; i < 4; ++i) {
        ra[i] = (wrow + i * 16 + fr) * 32 + sw;
        rc[i] = (wcol + i * 16 + fr) * 32 + sw;
    }

    issue(0, 0); issue(1, 1);
    floatx4 acc[4][4] = {};
    float s_loc[16] = {};
    float labacc[16] = {};
    int sc = 0, si = 2;
    for (int j = 0; j < T; ++j) {
        if (j < T - 1) { WAIT_VM4(); } else { WAIT_VM0(); }
        WAIT_LGKM();
        __builtin_amdgcn_s_barrier();
        if (j + 2 < T) { issue(j + 2, si); si = (si == 2) ? 0 : si + 1; }
        const unsigned short* As = Asm + sc * STG;
        const unsigned short* Bs = Bsm + sc * STG;
        sc = (sc == 2) ? 0 : sc + 1;
        short8 af[4], bf[4];
#pragma unroll
        for (int i = 0; i < 4; ++i) af[i] = *(const short8*)&As[ra[i]];
#pragma unroll
        for (int i = 0; i < 4; ++i) bf[i] = *(const short8*)&Bs[rc[i]];
#pragma unroll
        for (int rt = 0; rt < 4; ++rt)
#pragma unroll
            for (int ct = 0; ct < 4; ++ct)
                acc[rt][ct] = __builtin_amdgcn_mfma_f32_16x16x32_bf16(af[rt], bf[ct], acc[rt][ct], 0, 0, 0);

        if ((j & NKm) == NKm) {
            // per-chunk epilogue (vmem-free except head/last-iter bias).
            // |logit| < ~6 (xavier) -> max-free sum(exp) is fp32-safe.
            int ck = j >> nkb;
            int colb = colb0 + (ck << 7);
            float bv[4]; int vc[4];
#pragma unroll
            for (int ct = 0; ct < 4; ++ct) {
                vc[ct] = colb + wcol + ct * 16 + fr;
                bv[ct] = (bias != nullptr) ? ((vc[ct] < V) ? bias[vc[ct]] : 0.f) : 0.f;
            }
#pragma unroll
            for (int rt = 0; rt < 4; ++rt) {
#pragma unroll
                for (int r = 0; r < 4; ++r) {
                    int q = rt * 4 + r;
                    int lrow = wrow + rt * 16 + fk * 4 + r;
                    int lab = slab[lrow];
                    float s = 0.f;
#pragma unroll
                    for (int ct = 0; ct < 4; ++ct) {
                        float L = acc[rt][ct][r] + bv[ct];
                        labacc[q] = (vc[ct] == lab) ? L : labacc[q];   // register, no store
                        s += (vc[ct] < V) ? __expf(L) : 0.f;
                    }
                    s_loc[q] += s;
                }
#pragma unroll
                for (int ct = 0; ct < 4; ++ct)
                    acc[rt][ct] = (floatx4){0.f, 0.f, 0.f, 0.f};
            }
        }
    }

    // once per block: cross-lane reduce (sum-exp and label logit) + writes
#pragma unroll
    for (int q = 0; q < 16; ++q) {
        float s = s_loc[q];
        float lv = labacc[q];
#pragma unroll
        for (int msk = 1; msk < 16; msk <<= 1) {
            s += __shfl_xor(s, msk, 64);
            lv += __shfl_xor(lv, msk, 64);   // exact: at most one lane nonzero
        }
        if (fr == 0) {
            int rt = q >> 2, r = q & 3;
            int lrow = wrow + rt * 16 + fk * 4 + r;
            cs[lrow][wave & 1] = s;
            cl[lrow][wave & 1] = lv;
        }
    }
    __syncthreads();
    if (t < 128) {
        ps[(size_t)g * NTOK + row_base + t] = cs[t][0] + cs[t][1];
        int lr = slab[t] - colb0;
        if (lr >= 0 && lr < (cpga << 7))
            ll[row_base + t] = cl[t][0] + cl[t][1];
    }
}

// ---------------- merged per-row LSE reduce + NLL sum (3 segments) ----------------
__global__ void reduce_all_k(const float* __restrict__ ps0, const float* __restrict__ ll0,
                             const int* __restrict__ n0p, int nc0,
                             const float* __restrict__ ps1, const float* __restrict__ ll1,
                             const int* __restrict__ n1p, int nc1,
                             const float* __restrict__ psh, const float* __restrict__ llh, int nch,
                             float* __restrict__ loss) {
    int i = blockIdx.x * blockDim.x + threadIdx.x;
    int seg = i >> 12;
    int r = i & 4095;
    const float* ps; const float* ll; int nc, n;
    if (seg == 0)      { ps = ps0; ll = ll0; nc = nc0; n = *n0p; }
    else if (seg == 1) { ps = ps1; ll = ll1; nc = nc1; n = *n1p; }
    else               { ps = psh; ll = llh; nc = nch; n = NTOK; }
    float nll = 0.f;
    if (r < n) {
        float S = 0.f;
        for (int c = 0; c < nc; ++c) S += ps[(size_t)c * NTOK + r];
        nll = logf(S) - ll[r];
    }
    for (int off = 32; off; off >>= 1) nll += __shfl_down(nll, off, 64);
    if ((threadIdx.x & 63) == 0) atomicAdd(loss, nll);
}

__global__ void final_k(const float* __restrict__ loss, float* __restrict__ out) {
    out[0] = loss[0] * (1.0f / 4096.0f);
}

extern "C" void kernel_launch(void* const* d_in, const int* in_sizes, int n_in,
                              void* d_out, int out_size, void* d_ws, size_t ws_size,
                              hipStream_t stream) {
    const float* w_in   = (const float*)d_in[0];
    const int*   target = (const int*)d_in[1];
    const float* head_w = (const float*)d_in[2];
    const float* head_b = (const float*)d_in[3];
    const float* t0w1   = (const float*)d_in[4];
    const float* t0w2   = (const float*)d_in[5];
    const float* t1w1   = (const float*)d_in[6];
    const float* t1w2   = (const float*)d_in[7];
    float* out = (float*)d_out;

    char* wsb = (char*)d_ws;
    size_t o = 0;
    auto alloc = [&](size_t bytes) -> void* {
        void* p = wsb + o;
        o += (bytes + 255) & ~(size_t)255;
        return p;
    };
    float* loss = (float*)alloc(4);
    int* n0 = (int*)alloc(4);
    int* n1 = (int*)alloc(4);
    int* idx0 = (int*)alloc(NTOK * 4);
    int* lab0 = (int*)alloc(NTOK * 4);
    int* idx1 = (int*)alloc(NTOK * 4);
    int* lab1 = (int*)alloc(NTOK * 4);
    int* labh = (int*)alloc(NTOK * 4);

    const int SZ_WIN = NTOK * 1024, SZ_HW = 2002 * 1024, SZ_T0W1 = 1024 * 1024,
              SZ_T0W2 = 8000 * 1024, SZ_T1W1 = 256 * 1024, SZ_T1W2 = 40000 * 256;
    unsigned short* win_bf  = (unsigned short*)alloc((size_t)SZ_WIN * 2);
    unsigned short* hw_bf   = (unsigned short*)alloc((size_t)SZ_HW * 2);
    unsigned short* t0w1_bf = (unsigned short*)alloc((size_t)SZ_T0W1 * 2);
    unsigned short* t0w2_bf = (unsigned short*)alloc((size_t)SZ_T0W2 * 2);
    unsigned short* t1w1_bf = (unsigned short*)alloc((size_t)SZ_T1W1 * 2);
    unsigned short* t1w2_bf = (unsigned short*)alloc((size_t)SZ_T1W2 * 2);
    unsigned short* h0 = (unsigned short*)alloc((size_t)NTOK * 1024 * 2);
    unsigned short* h1 = (unsigned short*)alloc((size_t)NTOK * 256 * 2);

    const int NC0 = 63, NC1 = 79, NCH = 16;   // chunk-groups per segment
    float* ps0 = (float*)alloc((size_t)NC0 * NTOK * 4);
    float* ps1 = (float*)alloc((size_t)NC1 * NTOK * 4);
    float* psh = (float*)alloc((size_t)NCH * NTOK * 4);
    float* ll0 = (float*)alloc(NTOK * 4);
    float* ll1 = (float*)alloc(NTOK * 4);
    float* llh = (float*)alloc(NTOK * 4);

    dim3 blk(256);
    hipMemsetAsync(d_ws, 0, 768, stream);   // zero loss, n0, n1
    cvt_all_k<<<dim3(640, 7), blk, 0, stream>>>(
        w_in, win_bf, SZ_WIN, head_w, hw_bf, SZ_HW, t0w1, t0w1_bf, SZ_T0W1,
        t0w2, t0w2_bf, SZ_T0W2, t1w1, t1w1_bf, SZ_T1W1, t1w2, t1w2_bf, SZ_T1W2,
        target, idx0, lab0, n0, idx1, lab1, n1, labh);

    hgemm_all_k<<<320, blk, 0, stream>>>(win_bf, t0w1_bf, h0, idx0, n0,
                                         t1w1_bf, h1, idx1, n1);

    ce_all_k<<<2528 + 2016 + 512, blk, 0, stream>>>(
        h1, t1w2_bf, lab1, n1, ps1, ll1,
        h0, t0w2_bf, lab0, n0, ps0, ll0,
        win_bf, hw_bf, head_b, labh, psh, llh);

    reduce_all_k<<<3 * NTOK / 256, blk, 0, stream>>>(ps0, ll0, n0, NC0,
                                                     ps1, ll1, n1, NC1,
                                                     psh, llh, NCH, loss);
    final_k<<<1, 1, 0, stream>>>(loss, out);
}

// Round 8
// 412.861 us; speedup vs baseline: 1.1846x; 1.1846x over previous
//
#include <hip/hip_runtime.h>
#include <math.h>

#define NTOK 4096

typedef __attribute__((ext_vector_type(8))) short short8;
typedef __attribute__((ext_vector_type(4))) float floatx4;

static __device__ __forceinline__ unsigned short f2bf(float f) {
    unsigned int u = __float_as_uint(f);
    unsigned int r = (u + 0x7fffu + ((u >> 16) & 1u)) >> 16;
    return (unsigned short)r;
}

// async global->LDS, 16B per lane. LDS dest = wave-uniform base + lane*16.
static __device__ __forceinline__ void gload16(const void* g, void* l) {
    __builtin_amdgcn_global_load_lds(
        (const __attribute__((address_space(1))) void*)g,
        (__attribute__((address_space(3))) void*)(unsigned int)(unsigned long long)l,
        16, 0, 0);
}

#define WAIT_VM12() asm volatile("s_waitcnt vmcnt(12)" ::: "memory")
#define WAIT_VM8()  asm volatile("s_waitcnt vmcnt(8)" ::: "memory")
#define WAIT_VM6()  asm volatile("s_waitcnt vmcnt(6)" ::: "memory")
#define WAIT_VM4()  asm volatile("s_waitcnt vmcnt(4)" ::: "memory")
#define WAIT_VM0()  asm volatile("s_waitcnt vmcnt(0)" ::: "memory")
#define WAIT_LGKM() asm volatile("s_waitcnt lgkmcnt(0)" ::: "memory")

// ce stage: A 256x32 (16KB) + B 128x32 (8KB); 3 stages
#define ASTG 8192   // shorts per A stage
#define BSTG 4096   // shorts per B stage
// hgemm stage: 128x32 A and B (8KB each)
#define STG 4096

// ---------------- merged cvt (6 arrays) + compact (y==6) ----------------
__global__ void cvt_all_k(const float* __restrict__ s0, unsigned short* __restrict__ d0, int e0,
                          const float* __restrict__ s1, unsigned short* __restrict__ d1, int e1,
                          const float* __restrict__ s2, unsigned short* __restrict__ d2, int e2,
                          const float* __restrict__ s3, unsigned short* __restrict__ d3, int e3,
                          const float* __restrict__ s4, unsigned short* __restrict__ d4, int e4,
                          const float* __restrict__ s5, unsigned short* __restrict__ d5, int e5,
                          const int* __restrict__ target,
                          int* __restrict__ idx0, int* __restrict__ lab0, int* __restrict__ n0,
                          int* __restrict__ idx1, int* __restrict__ lab1, int* __restrict__ n1,
                          int* __restrict__ labh) {
    int y = blockIdx.y;
    if (y == 6) {
        int i = blockIdx.x * blockDim.x + threadIdx.x;
        if (i >= NTOK) return;
        int t = target[i];
        int ft = t;
        if (t >= 2000 && t < 10000) {
            int p = atomicAdd(n0, 1);
            idx0[p] = i; lab0[p] = t - 2000; ft = 2000;
        } else if (t >= 10000) {
            int p = atomicAdd(n1, 1);
            idx1[p] = i; lab1[p] = t - 10000; ft = 2001;
        }
        labh[i] = ft;
        return;
    }
    const float* s; unsigned short* d; int n;
    switch (y) {
        case 0: s = s0; d = d0; n = e0; break;
        case 1: s = s1; d = d1; n = e1; break;
        case 2: s = s2; d = d2; n = e2; break;
        case 3: s = s3; d = d3; n = e3; break;
        case 4: s = s4; d = d4; n = e4; break;
        default: s = s5; d = d5; n = e5; break;
    }
    int stride = gridDim.x * blockDim.x * 4;
    for (int i = (blockIdx.x * blockDim.x + threadIdx.x) * 4; i < n; i += stride) {
        float4 v = *(const float4*)(s + i);
        ushort4 o;
        o.x = f2bf(v.x); o.y = f2bf(v.y); o.z = f2bf(v.z); o.w = f2bf(v.w);
        *(ushort4*)(d + i) = o;
    }
}

// ---------------- merged gathered h-GEMM, 3-stage, issue-BEFORE-wait (round-4 proven) ----------------
__global__ __launch_bounds__(256)
void hgemm_all_k(const unsigned short* __restrict__ win,
                 const unsigned short* __restrict__ t0w1, unsigned short* __restrict__ h0o,
                 const int* __restrict__ idx0, const int* __restrict__ n0p,
                 const unsigned short* __restrict__ t1w1, unsigned short* __restrict__ h1o,
                 const int* __restrict__ idx1, const int* __restrict__ n1p) {
    __shared__ unsigned short Asm[3 * STG];
    __shared__ unsigned short Bsm[3 * STG];
    __shared__ int sidx[128];
    int bid = blockIdx.x;
    const unsigned short* B; unsigned short* H; const int* idx; int n, P, rb, cb;
    if (bid < 256) { rb = bid >> 3; cb = bid & 7; B = t0w1; H = h0o; idx = idx0; n = *n0p; P = 1024; }
    else { int b = bid - 256; rb = b >> 1; cb = b & 1; B = t1w1; H = h1o; idx = idx1; n = *n1p; P = 256; }
    const int K = 1024, T = 32;
    int row_base = rb * 128;
    if (row_base >= n) return;
    int col_base = cb * 128;
    int t = threadIdx.x;
    int wave = t >> 6, lane = t & 63;
    int wrow = (wave >> 1) * 64, wcol = (wave & 1) * 64;
    int fr = lane & 15, fk = lane >> 4;

    if (t < 128) { int r = row_base + t; sidx[t] = idx[r < n ? r : n - 1]; }
    __syncthreads();   // drains vmcnt: clean slate before manual pipeline

    int sr0 = wave * 32 + (lane >> 2);
    int sr1 = sr0 + 16;
    int c0l = lane & 3;
    int gc0 = c0l ^ ((sr0 >> 1) & 3);
    int gc1 = c0l ^ ((sr1 >> 1) & 3);
    const unsigned short* Ab0 = win + (size_t)sidx[sr0] * K + gc0 * 8;
    const unsigned short* Ab1 = win + (size_t)sidx[sr1] * K + gc1 * 8;
    const unsigned short* Bb0 = B + (size_t)(col_base + sr0) * K + gc0 * 8;
    const unsigned short* Bb1 = B + (size_t)(col_base + sr1) * K + gc1 * 8;

    auto issue = [&](int s, int slot) {
        int koff = s << 5;
        unsigned short* as = Asm + slot * STG + wave * 1024;
        unsigned short* bs = Bsm + slot * STG + wave * 1024;
        gload16(Ab0 + koff, as); gload16(Ab1 + koff, as + 512);
        gload16(Bb0 + koff, bs); gload16(Bb1 + koff, bs + 512);
    };

    int sw = (fk ^ ((fr >> 1) & 3)) * 8;
    int ra[4], rc[4];
#pragma unroll
    for (int i = 0; i < 4; ++i) {
        ra[i] = (wrow + i * 16 + fr) * 32 + sw;
        rc[i] = (wcol + i * 16 + fr) * 32 + sw;
    }

    issue(0, 0); issue(1, 1);
    floatx4 acc[4][4] = {};
    int sc = 0, si = 2;
    for (int j = 0; j < T; ++j) {
        if (j + 2 < T) { issue(j + 2, si); si = (si == 2) ? 0 : si + 1; }
        int rem = T - 1 - j;
        if (rem >= 2) { WAIT_VM8(); }
        else if (rem == 1) { WAIT_VM4(); }
        else { WAIT_VM0(); }
        WAIT_LGKM();
        __builtin_amdgcn_s_barrier();
        const unsigned short* As = Asm + sc * STG;
        const unsigned short* Bs = Bsm + sc * STG;
        sc = (sc == 2) ? 0 : sc + 1;
        short8 af[4], bf[4];
#pragma unroll
        for (int i = 0; i < 4; ++i) af[i] = *(const short8*)&As[ra[i]];
#pragma unroll
        for (int i = 0; i < 4; ++i) bf[i] = *(const short8*)&Bs[rc[i]];
#pragma unroll
        for (int rt = 0; rt < 4; ++rt)
#pragma unroll
            for (int ct = 0; ct < 4; ++ct)
                acc[rt][ct] = __builtin_amdgcn_mfma_f32_16x16x32_bf16(af[rt], bf[ct], acc[rt][ct], 0, 0, 0);
    }
#pragma unroll
    for (int rt = 0; rt < 4; ++rt)
#pragma unroll
        for (int r = 0; r < 4; ++r) {
            int row = row_base + wrow + rt * 16 + fk * 4 + r;
#pragma unroll
            for (int ct = 0; ct < 4; ++ct) {
                int col = col_base + wcol + ct * 16 + fr;
                H[(size_t)row * P + col] = f2bf(acc[rt][ct][r]);
            }
        }
}

// ---------------- CE: 256x128 tiles, one chunk per block, post-loop epilogue ----------------
// 3-stage, issue-BEFORE-wait (round-4 proven ordering: prefetch stays in flight
// across the vmcnt stall -> P ~ L/2 instead of L). 6 loads/wave/stage -> waits 12/6/0.
// seg1 (bid<5008):    tail1 V=40000 K=256  (16 rb x 313 ch), T=8
// seg0 (5008..6015):  tail0 V=8000  K=1024 (16 rb x 63 ch),  T=32
// segh (6016..6271):  head  V=2002  K=1024 (16 rb x 16 ch),  T=32, +bias
__global__ __launch_bounds__(256, 2)
void ce_all_k(const unsigned short* __restrict__ h1, const unsigned short* __restrict__ t1w2,
              const int* __restrict__ lab1, const int* __restrict__ n1p,
              float* __restrict__ ps1, float* __restrict__ ll1,
              const unsigned short* __restrict__ h0, const unsigned short* __restrict__ t0w2,
              const int* __restrict__ lab0, const int* __restrict__ n0p,
              float* __restrict__ ps0, float* __restrict__ ll0,
              const unsigned short* __restrict__ win, const unsigned short* __restrict__ hw,
              const float* __restrict__ head_b, const int* __restrict__ labh,
              float* __restrict__ psh, float* __restrict__ llh) {
    __shared__ unsigned short Asm[3 * ASTG];
    __shared__ unsigned short Bsm[3 * BSTG];
    __shared__ int slab[256];
    __shared__ float cs[256][2];
    __shared__ float cl[256][2];
    int bid = blockIdx.x;
    const unsigned short* A; const unsigned short* B; const float* bias = nullptr;
    const int* labels; int n, V, kbits, T, rb, ch;
    float* ps; float* ll;
    if (bid < 5008) {
        rb = bid / 313; ch = bid % 313;
        A = h1; B = t1w2; labels = lab1; n = *n1p; V = 40000; kbits = 8; T = 8;
        ps = ps1; ll = ll1;
    } else if (bid < 6016) {
        int b = bid - 5008; rb = b / 63; ch = b % 63;
        A = h0; B = t0w2; labels = lab0; n = *n0p; V = 8000; kbits = 10; T = 32;
        ps = ps0; ll = ll0;
    } else {
        int b = bid - 6016; rb = b >> 4; ch = b & 15;
        A = win; B = hw; labels = labh; n = NTOK; V = 2002; kbits = 10; T = 32;
        ps = psh; ll = llh; bias = head_b;
    }
    int row_base = rb * 256;
    if (row_base >= n) return;
    int colb = ch << 7;
    int Vm1 = V - 1;
    int t = threadIdx.x;
    int wave = t >> 6, lane = t & 63;
    int wrow = (wave >> 1) * 128, wcol = (wave & 1) * 64;
    int fr = lane & 15, fk = lane >> 4;

    slab[t] = labels[row_base + t];
    __syncthreads();   // drains vmcnt: clean slate before manual pipeline

    // staging: A 256x32 (4 instr/wave, 16-row steps), B 128x32 (2 instr/wave)
    int sra = wave * 64 + (lane >> 2);
    int srb = wave * 32 + (lane >> 2);
    int c0l = lane & 3;
    int gca = c0l ^ ((sra >> 1) & 3);   // +16 row steps preserve (r>>1)&3
    int gcb = c0l ^ ((srb >> 1) & 3);
    const unsigned short* Ap0 = A + (((size_t)(row_base + sra)) << kbits) + gca * 8;
    const unsigned short* Ap1 = A + (((size_t)(row_base + sra + 16)) << kbits) + gca * 8;
    const unsigned short* Ap2 = A + (((size_t)(row_base + sra + 32)) << kbits) + gca * 8;
    const unsigned short* Ap3 = A + (((size_t)(row_base + sra + 48)) << kbits) + gca * 8;
    int br0 = colb + srb;      if (br0 > Vm1) br0 = Vm1;
    int br1 = colb + srb + 16; if (br1 > Vm1) br1 = Vm1;
    const unsigned short* Bp0 = B + (((size_t)br0) << kbits) + gcb * 8;
    const unsigned short* Bp1 = B + (((size_t)br1) << kbits) + gcb * 8;

    auto issue = [&](int s, int slot) {
        int koff = s << 5;
        unsigned short* as = Asm + slot * ASTG + wave * 2048;
        unsigned short* bs = Bsm + slot * BSTG + wave * 1024;
        gload16(Ap0 + koff, as);        gload16(Ap1 + koff, as + 512);
        gload16(Ap2 + koff, as + 1024); gload16(Ap3 + koff, as + 1536);
        gload16(Bp0 + koff, bs);        gload16(Bp1 + koff, bs + 512);
    };

    int sw = (fk ^ ((fr >> 1) & 3)) * 8;
    int ra[8], rc[4];
#pragma unroll
    for (int i = 0; i < 8; ++i) ra[i] = (wrow + i * 16 + fr) * 32 + sw;
#pragma unroll
    for (int i = 0; i < 4; ++i) rc[i] = (wcol + i * 16 + fr) * 32 + sw;

    issue(0, 0); issue(1, 1);
    floatx4 acc[8][4] = {};
    int sc = 0, si = 2;
    for (int j = 0; j < T; ++j) {
        if (j + 2 < T) { issue(j + 2, si); si = (si == 2) ? 0 : si + 1; }
        int rem = T - 1 - j;
        if (rem >= 2) { WAIT_VM12(); }
        else if (rem == 1) { WAIT_VM6(); }
        else { WAIT_VM0(); }
        WAIT_LGKM();
        __builtin_amdgcn_s_barrier();
        const unsigned short* As = Asm + sc * ASTG;
        const unsigned short* Bs = Bsm + sc * BSTG;
        sc = (sc == 2) ? 0 : sc + 1;
        short8 af[8], bf[4];
#pragma unroll
        for (int i = 0; i < 8; ++i) af[i] = *(const short8*)&As[ra[i]];
#pragma unroll
        for (int i = 0; i < 4; ++i) bf[i] = *(const short8*)&Bs[rc[i]];
#pragma unroll
        for (int rt = 0; rt < 8; ++rt)
#pragma unroll
            for (int ct = 0; ct < 4; ++ct)
                acc[rt][ct] = __builtin_amdgcn_mfma_f32_16x16x32_bf16(af[rt], bf[ct], acc[rt][ct], 0, 0, 0);
    }

    // post-loop epilogue: bias + OOB mask + label capture + per-row sum(exp).
    // |logit| < ~6 (xavier) -> max-free sum(exp) is fp32-safe.
    float bv[4]; int vc[4];
#pragma unroll
    for (int ct = 0; ct < 4; ++ct) {
        vc[ct] = colb + wcol + ct * 16 + fr;
        bv[ct] = (bias != nullptr) ? ((vc[ct] < V) ? bias[vc[ct]] : 0.f) : 0.f;
    }
#pragma unroll
    for (int rt = 0; rt < 8; ++rt) {
#pragma unroll
        for (int r = 0; r < 4; ++r) {
            int lrow = wrow + rt * 16 + fk * 4 + r;
            int lab = slab[lrow];
            float s = 0.f, lv = 0.f;
#pragma unroll
            for (int ct = 0; ct < 4; ++ct) {
                float L = acc[rt][ct][r] + bv[ct];
                lv = (vc[ct] == lab) ? L : lv;
                s += (vc[ct] < V) ? __expf(L) : 0.f;
            }
#pragma unroll
            for (int msk = 1; msk < 16; msk <<= 1) {
                s += __shfl_xor(s, msk, 64);
                lv += __shfl_xor(lv, msk, 64);   // exact: at most one lane nonzero
            }
            if (fr == 0) { cs[lrow][wave & 1] = s; cl[lrow][wave & 1] = lv; }
        }
    }
    __syncthreads();
    ps[(size_t)ch * NTOK + row_base + t] = cs[t][0] + cs[t][1];
    int lr = slab[t] - colb;
    if (lr >= 0 && lr < 128)
        ll[row_base + t] = cl[t][0] + cl[t][1];
}

// ---------------- merged per-row LSE reduce + NLL sum (3 segments) ----------------
__global__ void reduce_all_k(const float* __restrict__ ps0, const float* __restrict__ ll0,
                             const int* __restrict__ n0p, int nc0,
                             const float* __restrict__ ps1, const float* __restrict__ ll1,
                             const int* __restrict__ n1p, int nc1,
                             const float* __restrict__ psh, const float* __restrict__ llh, int nch,
                             float* __restrict__ loss) {
    int i = blockIdx.x * blockDim.x + threadIdx.x;
    int seg = i >> 12;
    int r = i & 4095;
    const float* ps; const float* ll; int nc, n;
    if (seg == 0)      { ps = ps0; ll = ll0; nc = nc0; n = *n0p; }
    else if (seg == 1) { ps = ps1; ll = ll1; nc = nc1; n = *n1p; }
    else               { ps = psh; ll = llh; nc = nch; n = NTOK; }
    float nll = 0.f;
    if (r < n) {
        float S = 0.f;
        for (int c = 0; c < nc; ++c) S += ps[(size_t)c * NTOK + r];
        nll = logf(S) - ll[r];
    }
    for (int off = 32; off; off >>= 1) nll += __shfl_down(nll, off, 64);
    if ((threadIdx.x & 63) == 0) atomicAdd(loss, nll);
}

__global__ void final_k(const float* __restrict__ loss, float* __restrict__ out) {
    out[0] = loss[0] * (1.0f / 4096.0f);
}

extern "C" void kernel_launch(void* const* d_in, const int* in_sizes, int n_in,
                              void* d_out, int out_size, void* d_ws, size_t ws_size,
                              hipStream_t stream) {
    const float* w_in   = (const float*)d_in[0];
    const int*   target = (const int*)d_in[1];
    const float* head_w = (const float*)d_in[2];
    const float* head_b = (const float*)d_in[3];
    const float* t0w1   = (const float*)d_in[4];
    const float* t0w2   = (const float*)d_in[5];
    const float* t1w1   = (const float*)d_in[6];
    const float* t1w2   = (const float*)d_in[7];
    float* out = (float*)d_out;

    char* wsb = (char*)d_ws;
    size_t o = 0;
    auto alloc = [&](size_t bytes) -> void* {
        void* p = wsb + o;
        o += (bytes + 255) & ~(size_t)255;
        return p;
    };
    float* loss = (float*)alloc(4);
    int* n0 = (int*)alloc(4);
    int* n1 = (int*)alloc(4);
    int* idx0 = (int*)alloc(NTOK * 4);
    int* lab0 = (int*)alloc(NTOK * 4);
    int* idx1 = (int*)alloc(NTOK * 4);
    int* lab1 = (int*)alloc(NTOK * 4);
    int* labh = (int*)alloc(NTOK * 4);

    const int SZ_WIN = NTOK * 1024, SZ_HW = 2002 * 1024, SZ_T0W1 = 1024 * 1024,
              SZ_T0W2 = 8000 * 1024, SZ_T1W1 = 256 * 1024, SZ_T1W2 = 40000 * 256;
    unsigned short* win_bf  = (unsigned short*)alloc((size_t)SZ_WIN * 2);
    unsigned short* hw_bf   = (unsigned short*)alloc((size_t)SZ_HW * 2);
    unsigned short* t0w1_bf = (unsigned short*)alloc((size_t)SZ_T0W1 * 2);
    unsigned short* t0w2_bf = (unsigned short*)alloc((size_t)SZ_T0W2 * 2);
    unsigned short* t1w1_bf = (unsigned short*)alloc((size_t)SZ_T1W1 * 2);
    unsigned short* t1w2_bf = (unsigned short*)alloc((size_t)SZ_T1W2 * 2);
    unsigned short* h0 = (unsigned short*)alloc((size_t)NTOK * 1024 * 2);
    unsigned short* h1 = (unsigned short*)alloc((size_t)NTOK * 256 * 2);

    const int NC0 = 63, NC1 = 313, NCH = 16;   // chunks per segment (per-chunk partials)
    float* ps0 = (float*)alloc((size_t)NC0 * NTOK * 4);
    float* ps1 = (float*)alloc((size_t)NC1 * NTOK * 4);
    float* psh = (float*)alloc((size_t)NCH * NTOK * 4);
    float* ll0 = (float*)alloc(NTOK * 4);
    float* ll1 = (float*)alloc(NTOK * 4);
    float* llh = (float*)alloc(NTOK * 4);

    dim3 blk(256);
    hipMemsetAsync(d_ws, 0, 768, stream);   // zero loss, n0, n1
    cvt_all_k<<<dim3(640, 7), blk, 0, stream>>>(
        w_in, win_bf, SZ_WIN, head_w, hw_bf, SZ_HW, t0w1, t0w1_bf, SZ_T0W1,
        t0w2, t0w2_bf, SZ_T0W2, t1w1, t1w1_bf, SZ_T1W1, t1w2, t1w2_bf, SZ_T1W2,
        target, idx0, lab0, n0, idx1, lab1, n1, labh);

    hgemm_all_k<<<320, blk, 0, stream>>>(win_bf, t0w1_bf, h0, idx0, n0,
                                         t1w1_bf, h1, idx1, n1);

    ce_all_k<<<5008 + 1008 + 256, blk, 0, stream>>>(
        h1, t1w2_bf, lab1, n1, ps1, ll1,
        h0, t0w2_bf, lab0, n0, ps0, ll0,
        win_bf, hw_bf, head_b, labh, psh, llh);

    reduce_all_k<<<3 * NTOK / 256, blk, 0, stream>>>(ps0, ll0, n0, NC0,
                                                     ps1, ll1, n1, NC1,
                                                     psh, llh, NCH, loss);
    final_k<<<1, 1, 0, stream>>>(loss, out);
}